// Round 2
// baseline (218.540 us; speedup 1.0000x reference)
//
#include <hip/hip_runtime.h>
#include <math.h>

// GHM-C loss, restructured.
// Pass 1 (grid 2048 x 256): streams pred as float4, treating EVERY element as
// non-target: s = p, bce = softplus(p), nested accumulators
//   S_k = sum bce over {p >= T_k},  C_k = count{p >= T_k},  T_k = logit(k/10).
// (sum,count) pairs are accumulated as float2 vectors to get v_pk_fma_f32.
// Blocks 0..127 additionally correct the N target elements: remove the
// false-contribution of pred[i*C+t] and add its true-contribution (s = -p).
// Per-block partials (19 floats) -> d_ws. Pass 2 (1 block) reduces, differences
// the nested sums into per-bin values, and computes the loss.

#define PASS1_BLOCK 256
#define PASS1_GRID 2048

typedef float v2f __attribute__((ext_vector_type(2)));
typedef float v4f __attribute__((ext_vector_type(4)));

__device__ __forceinline__ void wave_red(float& v) {
#pragma unroll
    for (int off = 32; off > 0; off >>= 1) v += __shfl_down(v, off, 64);
}

// logit(k/10), k=1..9
__device__ __constant__ float kThresh[9] = {
    -2.1972246f, -1.3862944f, -0.84729786f, -0.40546511f, 0.0f,
    0.40546511f, 0.84729786f, 1.3862944f, 2.1972246f};

__device__ __forceinline__ void upd(float p, float& S0, v2f (&A)[9]) {
    float a = fabsf(p);
    float en = __expf(-a);
    float l1p = __logf(1.0f + en);
    float bce = fmaxf(p, 0.0f) + l1p;
    S0 += bce;
    v2f bv = {bce, 1.0f};
#pragma unroll
    for (int q = 0; q < 9; ++q) {
        float m = (p >= kThresh[q]) ? 1.0f : 0.0f;
        v2f mv = {m, m};
        A[q] += bv * mv;  // hopes for v_pk_fma_f32
    }
}

// correction for one target element with logit p: it was counted as
// non-target (s=p); replace with target contribution (s=-p).
__device__ __forceinline__ void upd_corr(float p, float& S0, v2f (&A)[9]) {
    float a = fabsf(p);
    float en = __expf(-a);
    float l1p = __logf(1.0f + en);
    float bf = fmaxf(p, 0.0f) + l1p;   // false contribution (remove)
    float bt = fmaxf(-p, 0.0f) + l1p;  // true contribution (add)
    S0 += bt - bf;
#pragma unroll
    for (int q = 0; q < 9; ++q) {
        float mf = (p >= kThresh[q]) ? 1.0f : 0.0f;
        float mt = (-p >= kThresh[q]) ? 1.0f : 0.0f;
        v2f d = {mt * bt - mf * bf, mt - mf};
        A[q] += d;
    }
}

__global__ __launch_bounds__(PASS1_BLOCK, 8) void ghmc_pass1(
    const float* __restrict__ pred, const int* __restrict__ target,
    float* __restrict__ blk, unsigned total4, unsigned totalNC, int N, int C) {
    float S0 = 0.0f;
    v2f A[9];
#pragma unroll
    for (int i = 0; i < 9; ++i) A[i] = (v2f){0.0f, 0.0f};

    unsigned tid = blockIdx.x * blockDim.x + threadIdx.x;
    unsigned stride = gridDim.x * blockDim.x;
    const v4f* p4 = (const v4f*)pred;

    for (unsigned v = tid; v < total4; v += stride) {
        v4f p = __builtin_nontemporal_load(p4 + v);
        upd(p[0], S0, A);
        upd(p[1], S0, A);
        upd(p[2], S0, A);
        upd(p[3], S0, A);
    }

    // tail (NC not divisible by 4): global thread 0
    if (tid == 0) {
        for (unsigned e = total4 << 2; e < totalNC; ++e) upd(pred[e], S0, A);
    }

    // correction: first ceil(N/256) blocks each handle 256 rows
    int row = (int)(blockIdx.x * blockDim.x + threadIdx.x);
    if (row < N) {
        int t = target[row];
        float p = pred[(unsigned)row * (unsigned)C + (unsigned)t];
        upd_corr(p, S0, A);
    }

    // reduce 19 floats across the block
    float vals[19];
    vals[0] = S0;
#pragma unroll
    for (int i = 0; i < 9; ++i) {
        vals[1 + i] = A[i].x;
        vals[10 + i] = A[i].y;
    }
#pragma unroll
    for (int i = 0; i < 19; ++i) wave_red(vals[i]);

    __shared__ float sP[PASS1_BLOCK / 64][19];
    int wid = threadIdx.x >> 6;
    int lane = threadIdx.x & 63;
    if (lane == 0) {
#pragma unroll
        for (int i = 0; i < 19; ++i) sP[wid][i] = vals[i];
    }
    __syncthreads();
    if (threadIdx.x == 0) {
        const int nw = PASS1_BLOCK / 64;
#pragma unroll
        for (int i = 0; i < 19; ++i) {
            float acc = 0.0f;
            for (int w = 0; w < nw; ++w) acc += sP[w][i];
            blk[(unsigned)blockIdx.x * 19u + (unsigned)i] = acc;
        }
    }
}

__global__ __launch_bounds__(256) void ghmc_pass2(
    const float* __restrict__ blk, float* __restrict__ out, int nblocks,
    float totalNC) {
    float P[19];
#pragma unroll
    for (int i = 0; i < 19; ++i) P[i] = 0.0f;

    for (int b = threadIdx.x; b < nblocks; b += blockDim.x) {
#pragma unroll
        for (int i = 0; i < 19; ++i) P[i] += blk[(unsigned)b * 19u + (unsigned)i];
    }
#pragma unroll
    for (int i = 0; i < 19; ++i) wave_red(P[i]);

    __shared__ float sP[4][19];
    int wid = threadIdx.x >> 6;
    int lane = threadIdx.x & 63;
    if (lane == 0) {
#pragma unroll
        for (int i = 0; i < 19; ++i) sP[wid][i] = P[i];
    }
    __syncthreads();
    if (threadIdx.x == 0) {
        float Sv[11], Cv[11];
        for (int i = 0; i < 19; ++i) {
            float a = 0.0f;
            for (int w = 0; w < 4; ++w) a += sP[w][i];
            P[i] = a;
        }
        for (int i = 0; i < 10; ++i) Sv[i] = P[i];
        Sv[10] = 0.0f;
        Cv[0] = totalNC;
        for (int i = 1; i < 10; ++i) Cv[i] = P[9 + i];
        Cv[10] = 0.0f;

        int nonempty = 0;
        for (int b = 0; b < 10; ++b)
            if (Cv[b] - Cv[b + 1] > 0.5f) nonempty++;
        float n = fmaxf((float)nonempty, 1.0f);

        float loss = 0.0f;
        for (int b = 0; b < 10; ++b) {
            float cnt = Cv[b] - Cv[b + 1];
            if (cnt > 0.5f) {
                float bs = Sv[b] - Sv[b + 1];
                loss += bs / (cnt * n);
            }
        }
        out[0] = loss;  // LOSS_WEIGHT = 1.0
    }
}

extern "C" void kernel_launch(void* const* d_in, const int* in_sizes, int n_in,
                              void* d_out, int out_size, void* d_ws, size_t ws_size,
                              hipStream_t stream) {
    const float* pred = (const float*)d_in[0];
    const int* target = (const int*)d_in[1];
    int NC = in_sizes[0];
    int N = in_sizes[1];
    int C = NC / N;
    unsigned total4 = (unsigned)(NC / 4);

    int blocks = PASS1_GRID;
    size_t per_block = 19 * sizeof(float);
    if (ws_size < (size_t)blocks * per_block) {
        size_t maxb = ws_size / per_block;
        blocks = (int)(maxb > 0 ? maxb : 1);
    }
    // correction requires grid*block >= N (each row corrected exactly once)
    // N=32768 needs >=128 blocks; PASS1_GRID=2048 satisfies this.

    float* blkbuf = (float*)d_ws;

    ghmc_pass1<<<blocks, PASS1_BLOCK, 0, stream>>>(pred, target, blkbuf, total4,
                                                   (unsigned)NC, N, C);
    ghmc_pass2<<<1, 256, 0, stream>>>(blkbuf, (float*)d_out, blocks, (float)NC);
}